// Round 1
// baseline (2931.245 us; speedup 1.0000x reference)
//
#include <hip/hip_runtime.h>
#include <cstdio>
#include <cstdint>

// Problem constants (from setup_inputs; fixed for this problem)
#define TOK   32760      // N_t * S
#define DIM   1536
#define ENCD  768
#define NA    32
#define NT    21
#define SS    1560
#define HEADS 12
#define HD    128
#define KVROWS (NT * NA)   // 672

using f32x4  = __attribute__((ext_vector_type(4))) float;
using bf16x8 = __attribute__((ext_vector_type(8))) short;

__device__ __forceinline__ ushort bf16hi(float f) {
  unsigned u = __float_as_uint(f);
  return (ushort)((u + 0x7FFFu + ((u >> 16) & 1u)) >> 16);   // RNE
}
__device__ __forceinline__ float bf16tof(ushort h) {
  return __uint_as_float(((unsigned)h) << 16);
}

__device__ __forceinline__ void gload16(const void* g, void* l) {
  __builtin_amdgcn_global_load_lds((const __attribute__((address_space(1))) void*)g,
                                   (__attribute__((address_space(3))) void*)l,
                                   16, 0, 0);
}

// ---------------------------------------------------------------------------
// 1) min/max of the two attn-map rows + per-token rotary position
//    pos = (m0>=m1) ? norm(m0)->[0,4] : norm(m1)->[20,24]   (argmax ties -> 0)
// ---------------------------------------------------------------------------
__global__ __launch_bounds__(1024) void minmax_pos_kernel(
    const float* __restrict__ m, float* __restrict__ pos, int N) {
  __shared__ float red[4][16];
  __shared__ float fin[4];
  int tid = threadIdx.x;
  float mn0 = 3.4e38f, mx0 = -3.4e38f, mn1 = 3.4e38f, mx1 = -3.4e38f;
  for (int i = tid; i < N; i += 1024) {
    float a = m[i], b = m[N + i];
    mn0 = fminf(mn0, a); mx0 = fmaxf(mx0, a);
    mn1 = fminf(mn1, b); mx1 = fmaxf(mx1, b);
  }
  #pragma unroll
  for (int o = 32; o >= 1; o >>= 1) {
    mn0 = fminf(mn0, __shfl_xor(mn0, o)); mx0 = fmaxf(mx0, __shfl_xor(mx0, o));
    mn1 = fminf(mn1, __shfl_xor(mn1, o)); mx1 = fmaxf(mx1, __shfl_xor(mx1, o));
  }
  int wid = tid >> 6, ln = tid & 63;
  if (ln == 0) { red[0][wid] = mn0; red[1][wid] = mx0; red[2][wid] = mn1; red[3][wid] = mx1; }
  __syncthreads();
  if (tid == 0) {
    float a = red[0][0], b = red[1][0], c = red[2][0], d = red[3][0];
    for (int i = 1; i < 16; i++) {
      a = fminf(a, red[0][i]); b = fmaxf(b, red[1][i]);
      c = fminf(c, red[2][i]); d = fmaxf(d, red[3][i]);
    }
    fin[0] = a; fin[1] = b; fin[2] = c; fin[3] = d;
  }
  __syncthreads();
  float mn0f = fin[0], sc0 = 4.0f / (fin[1] - fin[0] + 1e-8f);
  float mn1f = fin[2], sc1 = 4.0f / (fin[3] - fin[2] + 1e-8f);
  for (int i = tid; i < N; i += 1024) {
    float a = m[i], b = m[N + i];
    float h1 = (a - mn0f) * sc0;            // [0,4]
    float h2 = (b - mn1f) * sc1 + 20.0f;    // [20,24]
    pos[i] = (a >= b) ? h1 : h2;
  }
}

// ---------------------------------------------------------------------------
// 2) fp32 -> (bf16 hi | bf16 lo) split, rows of length K -> rows of length 2K
// ---------------------------------------------------------------------------
__global__ void conv_hilo_kernel(const float* __restrict__ in, ushort* __restrict__ out,
                                 int M, int K) {
  int total4 = M * (K / 4);
  for (int idx = blockIdx.x * blockDim.x + threadIdx.x; idx < total4;
       idx += gridDim.x * blockDim.x) {
    int e = idx * 4;
    int row = e / K;
    int k = e - row * K;
    float4 v = *(const float4*)(in + e);
    float fs[4] = {v.x, v.y, v.z, v.w};
    ushort hs[4], ls[4];
    #pragma unroll
    for (int t = 0; t < 4; t++) {
      hs[t] = bf16hi(fs[t]);
      float hf = bf16tof(hs[t]);
      ls[t] = bf16hi(fs[t] - hf);
    }
    ushort* po = out + (size_t)row * (2 * K) + k;
    *(ushort4*)(po)     = make_ushort4(hs[0], hs[1], hs[2], hs[3]);
    *(ushort4*)(po + K) = make_ushort4(ls[0], ls[1], ls[2], ls[3]);
  }
}

// ---------------------------------------------------------------------------
// 3) Split-bf16 NT GEMM:  C[M,N] = A[M,K] * B[N,K]^T + bias,  fp32-accurate via
//    3 terms: Ahi*Bhi + Ahi*Blo + Alo*Bhi.  A,B stored as (hi|lo) rows of 2K.
//    128x128 tile, BK=64, 4 waves x 4x4 MFMA 16x16x32 bf16, global_load_lds.
//    LDS tiles are k-granule-major: [kg][row][8] (granule = 8 bf16 = 16 B).
// ---------------------------------------------------------------------------
__global__ __launch_bounds__(256) void gemm_bf16s_kernel(
    const ushort* __restrict__ A, const ushort* __restrict__ B,
    const float* __restrict__ bias, float* __restrict__ C,
    int M, int N, int K) {
  __shared__ __align__(16) ushort lA[8][128][8];   // 16 KB
  __shared__ __align__(16) ushort lB[8][128][8];   // 16 KB
  const int tid = threadIdx.x;
  const int lane = tid & 63;
  const int w = tid >> 6;          // wave 0..3
  const int wm = w >> 1, wn = w & 1;
  const int quad = lane >> 4, m16 = lane & 15;
  const int m0 = blockIdx.y * 128, n0 = blockIdx.x * 128;
  const int lda = 2 * K;

  f32x4 acc[4][4];
  #pragma unroll
  for (int i = 0; i < 4; i++)
    #pragma unroll
    for (int j = 0; j < 4; j++) acc[i][j] = (f32x4){0.f, 0.f, 0.f, 0.f};

  const int nIter = K / 64;
  for (int seg = 0; seg < 3; seg++) {
    const int aoff = (seg == 2) ? K : 0;   // A: hi, hi, lo
    const int boff = (seg == 1) ? K : 0;   // B: hi, lo, hi
    for (int kt = 0; kt < nIter; kt++) {
      const int kA = aoff + kt * 64;
      const int kB = boff + kt * 64;
      __syncthreads();                     // prior compute done before overwrite
      #pragma unroll
      for (int i = 0; i < 4; i++) {
        const int s = w * 4 + i;           // staging instr 0..15
        const int kg = s >> 1;             // k-granule 0..7
        const int mr = ((s & 1) << 6) + lane;  // row-in-tile 0..127
        int gm = m0 + mr; if (gm >= M) gm = M - 1;
        gload16(A + (size_t)gm * lda + (kA + kg * 8), &lA[0][0][0] + s * 512);
        int gn = n0 + mr; if (gn >= N) gn = N - 1;
        gload16(B + (size_t)gn * lda + (kB + kg * 8), &lB[0][0][0] + s * 512);
      }
      __syncthreads();                     // vmcnt(0) drain -> tiles ready
      #pragma unroll
      for (int kk = 0; kk < 2; kk++) {
        bf16x8 fa[4], fb[4];
        #pragma unroll
        for (int i = 0; i < 4; i++) {
          fa[i] = *(const bf16x8*)(&lA[kk * 4 + quad][wm * 64 + i * 16 + m16][0]);
          fb[i] = *(const bf16x8*)(&lB[kk * 4 + quad][wn * 64 + i * 16 + m16][0]);
        }
        #pragma unroll
        for (int i = 0; i < 4; i++)
          #pragma unroll
          for (int j = 0; j < 4; j++)
            acc[i][j] = __builtin_amdgcn_mfma_f32_16x16x32_bf16(fa[i], fb[j], acc[i][j], 0, 0, 0);
      }
    }
  }
  // epilogue: D row=(lane>>4)*4+reg, col=lane&15  [m89-verified layout]
  #pragma unroll
  for (int j = 0; j < 4; j++) {
    const int col = n0 + wn * 64 + j * 16 + m16;
    const float bv = bias[col];
    #pragma unroll
    for (int i = 0; i < 4; i++) {
      const int rbase = m0 + wm * 64 + i * 16 + quad * 4;
      #pragma unroll
      for (int r = 0; r < 4; r++) {
        const int row = rbase + r;
        if (row < M) C[(size_t)row * N + col] = acc[i][j][r] + bv;
      }
    }
  }
}

// ---------------------------------------------------------------------------
// 4) Fused attention: one wave per (t, head, 30-row chunk).
//    - k cached in 64 VGPRs with bucket-centre RoPE applied at load
//    - v cached in 64 VGPRs
//    - q RoPE applied at load (pos[n]); softmax over 32 via shuffles
//    - epilogue writes (hi|lo) bf16 split directly in proj-GEMM A layout
// ---------------------------------------------------------------------------
__global__ __launch_bounds__(64) void attn_kernel(
    const float* __restrict__ q, const float* __restrict__ kv,
    const float* __restrict__ pos, ushort* __restrict__ attA) {
  const int chunk = blockIdx.x;   // 0..51
  const int head  = blockIdx.y;   // 0..11
  const int t     = blockIdx.z;   // 0..20
  const int lane  = threadIdx.x;  // 0..63
  const int a = lane & 31, h = lane >> 5;
  const float L2_10000_64 = 13.287712379549449f / 64.0f;  // log2(10000)/64

  // ---- preload k (roped) : lane holds k[a][h*64 .. h*64+63]
  float kreg[64];
  const float* krow = kv + (size_t)(t * NA + a) * (2 * DIM) + head * HD + h * 64;
  #pragma unroll
  for (int j = 0; j < 16; j++) ((float4*)kreg)[j] = ((const float4*)krow)[j];
  const float pk = (a < 16) ? 2.0f : 22.0f;
  #pragma unroll
  for (int j = 0; j < 32; j++) {
    int ip = h * 32 + j;                        // pair index within head_dim
    float fr = exp2f(-(float)ip * L2_10000_64); // 10000^(-ip/64)
    float sn, cs; sincosf(pk * fr, &sn, &cs);
    float x0 = kreg[2 * j], x1 = kreg[2 * j + 1];
    kreg[2 * j]     = x0 * cs - x1 * sn;
    kreg[2 * j + 1] = x1 * cs + x0 * sn;
  }
  // ---- preload v : lane holds v[a][lane], v[a][lane+64]
  float vr0[32], vr1[32];
  const float* vbase = kv + (size_t)(t * NA) * (2 * DIM) + DIM + head * HD;
  #pragma unroll
  for (int aa = 0; aa < 32; aa++) {
    vr0[aa] = vbase[(size_t)aa * (2 * DIM) + lane];
    vr1[aa] = vbase[(size_t)aa * (2 * DIM) + 64 + lane];
  }

  __shared__ float qs[128];
  __shared__ float Ps[32];
  const float myfreq = exp2f(-(float)lane * L2_10000_64);

  for (int r = 0; r < 30; r++) {
    const int n = t * SS + chunk * 30 + r;
    // q load + rope (lane owns pair `lane`: dims 2*lane, 2*lane+1)
    float2 qp = ((const float2*)(q + (size_t)n * DIM + head * HD))[lane];
    float p = pos[n];
    float sn, cs; sincosf(p * myfreq, &sn, &cs);
    qs[2 * lane]     = qp.x * cs - qp.y * sn;
    qs[2 * lane + 1] = qp.y * cs + qp.x * sn;
    __syncthreads();
    // scores: lane (a,h) partial over d in [h*64, h*64+64)
    float accd = 0.f;
    #pragma unroll
    for (int j4 = 0; j4 < 16; j4++) {
      float4 qq = ((const float4*)(qs + h * 64))[j4];   // 2-address broadcast
      accd += qq.x * kreg[j4 * 4] + qq.y * kreg[j4 * 4 + 1] +
              qq.z * kreg[j4 * 4 + 2] + qq.w * kreg[j4 * 4 + 3];
    }
    accd += __shfl_xor(accd, 32);
    accd *= 0.08838834764831845f;    // 1/sqrt(128)
    // softmax over the 32 a-lanes (both halves mirror)
    float mx = accd;
    #pragma unroll
    for (int o = 16; o >= 1; o >>= 1) mx = fmaxf(mx, __shfl_xor(mx, o));
    float e = __expf(accd - mx);
    float sum = e;
    #pragma unroll
    for (int o = 16; o >= 1; o >>= 1) sum += __shfl_xor(sum, o);
    float P = e / sum;
    if (lane < 32) Ps[lane] = P;
    __syncthreads();
    // PV: lane accumulates out[lane], out[lane+64]
    float o0 = 0.f, o1 = 0.f;
    #pragma unroll
    for (int aa = 0; aa < 32; aa++) {
      float pa = Ps[aa];               // broadcast read
      o0 += pa * vr0[aa];
      o1 += pa * vr1[aa];
    }
    // write hi|lo split in proj-GEMM A layout (row length 2*DIM)
    size_t base = (size_t)n * (2 * DIM);
    int c0 = head * HD + lane;
    ushort h0 = bf16hi(o0); ushort l0 = bf16hi(o0 - bf16tof(h0));
    ushort h1 = bf16hi(o1); ushort l1 = bf16hi(o1 - bf16tof(h1));
    attA[base + c0]            = h0;
    attA[base + DIM + c0]      = l0;
    attA[base + c0 + 64]       = h1;
    attA[base + DIM + c0 + 64] = l1;
    __syncthreads();   // protect qs/Ps before next row overwrites
  }
}

// ---------------------------------------------------------------------------
extern "C" void kernel_launch(void* const* d_in, const int* in_sizes, int n_in,
                              void* d_out, int out_size, void* d_ws, size_t ws_size,
                              hipStream_t stream) {
  const float* x      = (const float*)d_in[0];
  const float* enc    = (const float*)d_in[1];
  const float* xmap   = (const float*)d_in[2];
  const float* q_w    = (const float*)d_in[3];
  const float* q_b    = (const float*)d_in[4];
  const float* kv_w   = (const float*)d_in[5];
  const float* kv_b   = (const float*)d_in[6];
  const float* proj_w = (const float*)d_in[7];
  const float* proj_b = (const float*)d_in[8];
  float* out = (float*)d_out;
  char* ws = (char*)d_ws;

  // workspace layout (bytes)
  const size_t OFF_POS  = 0;                           // 32760 f32
  const size_t OFF_APR  = 131072;                      // 32760 x 3072 bf16 (hi|lo)
  const size_t OFF_Q    = OFF_APR + 201277440;         // 32760 x 1536 f32
  const size_t OFF_KV   = OFF_Q   + 201277440;         // 672 x 3072 f32
  const size_t OFF_BQ   = OFF_KV  + 8257536;           // 1536 x 3072 bf16
  const size_t OFF_BKV  = OFF_BQ  + 9437184;           // 3072 x 1536 bf16
  const size_t OFF_BP   = OFF_BKV + 9437184;           // 1536 x 3072 bf16
  const size_t OFF_AKV  = OFF_BP  + 9437184;           // 672 x 1536 bf16
  const size_t TOTAL    = OFF_AKV + 2064384;           // ~421 MB
  if (ws_size < TOTAL) {
    fprintf(stderr, "kernel_launch: ws_size %zu < needed %zu\n", ws_size, TOTAL);
    return;
  }
  float*  pos   = (float*)(ws + OFF_POS);
  ushort* Apr   = (ushort*)(ws + OFF_APR);
  float*  qbuf  = (float*)(ws + OFF_Q);
  float*  kvbuf = (float*)(ws + OFF_KV);
  ushort* Bq    = (ushort*)(ws + OFF_BQ);
  ushort* Bkv   = (ushort*)(ws + OFF_BKV);
  ushort* Bp    = (ushort*)(ws + OFF_BP);
  ushort* Akv   = (ushort*)(ws + OFF_AKV);

  // 1) routing positions
  minmax_pos_kernel<<<1, 1024, 0, stream>>>(xmap, pos, TOK);
  // 2) hi/lo conversions
  conv_hilo_kernel<<<2048, 256, 0, stream>>>(x,      Apr, TOK,    DIM);
  conv_hilo_kernel<<<256,  256, 0, stream>>>(q_w,    Bq,  DIM,    DIM);
  conv_hilo_kernel<<<256,  256, 0, stream>>>(kv_w,   Bkv, 2*DIM,  ENCD);
  conv_hilo_kernel<<<64,   256, 0, stream>>>(enc,    Akv, KVROWS, ENCD);
  conv_hilo_kernel<<<256,  256, 0, stream>>>(proj_w, Bp,  DIM,    DIM);
  // 3) Q = x @ q_w^T + q_b
  gemm_bf16s_kernel<<<dim3(DIM/128, (TOK+127)/128), 256, 0, stream>>>(
      Apr, Bq, q_b, qbuf, TOK, DIM, DIM);
  // 4) KV = enc @ kv_w^T + kv_b
  gemm_bf16s_kernel<<<dim3(2*DIM/128, (KVROWS+127)/128), 256, 0, stream>>>(
      Akv, Bkv, kv_b, kvbuf, KVROWS, 2*DIM, ENCD);
  // 5) fused rope+attention, writes hi|lo att into Apr (x-conv dead by now)
  attn_kernel<<<dim3(52, HEADS, NT), 64, 0, stream>>>(qbuf, kvbuf, pos, Apr);
  // 6) out = att @ proj_w^T + proj_b
  gemm_bf16s_kernel<<<dim3(DIM/128, (TOK+127)/128), 256, 0, stream>>>(
      Apr, Bp, proj_b, out, TOK, DIM, DIM);
}

// Round 2
// 2433.405 us; speedup vs baseline: 1.2046x; 1.2046x over previous
//
#include <hip/hip_runtime.h>
#include <cstdio>
#include <cstdint>

// Problem constants (from setup_inputs; fixed for this problem)
#define TOK   32760      // N_t * S
#define DIM   1536
#define ENCD  768
#define NA    32
#define NT    21
#define SS    1560
#define HEADS 12
#define HD    128
#define KVROWS (NT * NA)   // 672

using f32x4  = __attribute__((ext_vector_type(4))) float;
using bf16x8 = __attribute__((ext_vector_type(8))) short;

__device__ __forceinline__ ushort bf16hi(float f) {
  unsigned u = __float_as_uint(f);
  return (ushort)((u + 0x7FFFu + ((u >> 16) & 1u)) >> 16);   // RNE
}
__device__ __forceinline__ float bf16tof(ushort h) {
  return __uint_as_float(((unsigned)h) << 16);
}

__device__ __forceinline__ void gload16(const void* g, void* l) {
  __builtin_amdgcn_global_load_lds((const __attribute__((address_space(1))) void*)g,
                                   (__attribute__((address_space(3))) void*)l,
                                   16, 0, 0);
}

// ---------------------------------------------------------------------------
// 1) min/max of the two attn-map rows + per-token rotary position
//    pos = (m0>=m1) ? norm(m0)->[0,4] : norm(m1)->[20,24]   (argmax ties -> 0)
// ---------------------------------------------------------------------------
__global__ __launch_bounds__(1024) void minmax_pos_kernel(
    const float* __restrict__ m, float* __restrict__ pos, int N) {
  __shared__ float red[4][16];
  __shared__ float fin[4];
  int tid = threadIdx.x;
  float mn0 = 3.4e38f, mx0 = -3.4e38f, mn1 = 3.4e38f, mx1 = -3.4e38f;
  for (int i = tid; i < N; i += 1024) {
    float a = m[i], b = m[N + i];
    mn0 = fminf(mn0, a); mx0 = fmaxf(mx0, a);
    mn1 = fminf(mn1, b); mx1 = fmaxf(mx1, b);
  }
  #pragma unroll
  for (int o = 32; o >= 1; o >>= 1) {
    mn0 = fminf(mn0, __shfl_xor(mn0, o)); mx0 = fmaxf(mx0, __shfl_xor(mx0, o));
    mn1 = fminf(mn1, __shfl_xor(mn1, o)); mx1 = fmaxf(mx1, __shfl_xor(mx1, o));
  }
  int wid = tid >> 6, ln = tid & 63;
  if (ln == 0) { red[0][wid] = mn0; red[1][wid] = mx0; red[2][wid] = mn1; red[3][wid] = mx1; }
  __syncthreads();
  if (tid == 0) {
    float a = red[0][0], b = red[1][0], c = red[2][0], d = red[3][0];
    for (int i = 1; i < 16; i++) {
      a = fminf(a, red[0][i]); b = fmaxf(b, red[1][i]);
      c = fminf(c, red[2][i]); d = fmaxf(d, red[3][i]);
    }
    fin[0] = a; fin[1] = b; fin[2] = c; fin[3] = d;
  }
  __syncthreads();
  float mn0f = fin[0], sc0 = 4.0f / (fin[1] - fin[0] + 1e-8f);
  float mn1f = fin[2], sc1 = 4.0f / (fin[3] - fin[2] + 1e-8f);
  for (int i = tid; i < N; i += 1024) {
    float a = m[i], b = m[N + i];
    float h1 = (a - mn0f) * sc0;            // [0,4]
    float h2 = (b - mn1f) * sc1 + 20.0f;    // [20,24]
    pos[i] = (a >= b) ? h1 : h2;
  }
}

// ---------------------------------------------------------------------------
// 2) fp32 -> (bf16 hi | bf16 lo) split, rows of length K -> rows of length 2K
// ---------------------------------------------------------------------------
__global__ void conv_hilo_kernel(const float* __restrict__ in, ushort* __restrict__ out,
                                 int M, int K) {
  int total4 = M * (K / 4);
  for (int idx = blockIdx.x * blockDim.x + threadIdx.x; idx < total4;
       idx += gridDim.x * blockDim.x) {
    int e = idx * 4;
    int row = e / K;
    int k = e - row * K;
    float4 v = *(const float4*)(in + e);
    float fs[4] = {v.x, v.y, v.z, v.w};
    ushort hs[4], ls[4];
    #pragma unroll
    for (int t = 0; t < 4; t++) {
      hs[t] = bf16hi(fs[t]);
      float hf = bf16tof(hs[t]);
      ls[t] = bf16hi(fs[t] - hf);
    }
    ushort* po = out + (size_t)row * (2 * K) + k;
    *(ushort4*)(po)     = make_ushort4(hs[0], hs[1], hs[2], hs[3]);
    *(ushort4*)(po + K) = make_ushort4(ls[0], ls[1], ls[2], ls[3]);
  }
}

// ---------------------------------------------------------------------------
// 3) Split-bf16 NT GEMM:  C[M,N] = A[M,K] * B[N,K]^T + bias,  fp32-accurate via
//    3 terms: Ahi*Bhi + Ahi*Blo + Alo*Bhi.  A,B stored as (hi|lo) rows of 2K.
//    128x128 tile, BK=64, 4 waves x 4x4 MFMA 16x16x32 bf16, global_load_lds.
//    R1 restructure: stage ALL FOUR tiles (Ahi,Alo,Bhi,Blo = 64 KB) once per
//    K-chunk, then run the 3 product passes between a single barrier pair
//    (96 MFMA/wave per barrier instead of 32). XCD swizzle: the nx column
//    blocks of each row panel share flat%8 -> same XCD L2 holds the A panel.
// ---------------------------------------------------------------------------
__global__ __launch_bounds__(256, 2) void gemm_bf16s_kernel(
    const ushort* __restrict__ A, const ushort* __restrict__ B,
    const float* __restrict__ bias, float* __restrict__ C,
    int M, int N, int K) {
  __shared__ __align__(16) ushort lAh[8][128][8];   // 16 KB
  __shared__ __align__(16) ushort lAl[8][128][8];   // 16 KB
  __shared__ __align__(16) ushort lBh[8][128][8];   // 16 KB
  __shared__ __align__(16) ushort lBl[8][128][8];   // 16 KB
  const int tid = threadIdx.x;
  const int lane = tid & 63;
  const int w = tid >> 6;          // wave 0..3
  const int wm = w >> 1, wn = w & 1;
  const int quad = lane >> 4, m16 = lane & 15;

  // XCD-aware swizzle: keep a full row panel (all nx column tiles) on one XCD
  int bx = blockIdx.x, by = blockIdx.y;
  {
    const int nx = gridDim.x, ny = gridDim.y;
    if ((ny & 7) == 0) {
      int flat = by * nx + bx;
      int xcd = flat & 7, s = flat >> 3;
      int panel = s / nx;
      bx = s - panel * nx;
      by = panel * 8 + xcd;
    }
  }
  const int m0 = by * 128, n0 = bx * 128;
  const int lda = 2 * K;

  f32x4 acc[4][4];
  #pragma unroll
  for (int i = 0; i < 4; i++)
    #pragma unroll
    for (int j = 0; j < 4; j++) acc[i][j] = (f32x4){0.f, 0.f, 0.f, 0.f};

  const int nIter = K / 64;
  for (int kt = 0; kt < nIter; kt++) {
    const int kH = kt * 64;        // hi half
    const int kL = K + kt * 64;    // lo half
    __syncthreads();               // prior compute done before overwrite
    #pragma unroll
    for (int i = 0; i < 4; i++) {
      const int s = w * 4 + i;     // staging instr 0..15 per tile
      const int kg = s >> 1;       // k-granule 0..7
      const int mr = ((s & 1) << 6) + lane;  // row-in-tile 0..127
      int gm = m0 + mr; if (gm >= M) gm = M - 1;
      const ushort* arow = A + (size_t)gm * lda;
      gload16(arow + kH + kg * 8, &lAh[0][0][0] + s * 512);
      gload16(arow + kL + kg * 8, &lAl[0][0][0] + s * 512);
      int gn = n0 + mr; if (gn >= N) gn = N - 1;
      const ushort* brow = B + (size_t)gn * lda;
      gload16(brow + kH + kg * 8, &lBh[0][0][0] + s * 512);
      gload16(brow + kL + kg * 8, &lBl[0][0][0] + s * 512);
    }
    __syncthreads();               // vmcnt(0) drain -> all 4 tiles ready
    #pragma unroll
    for (int kk = 0; kk < 2; kk++) {
      bf16x8 fa[4], fb[4];
      // pass 1: Ahi x Bhi
      #pragma unroll
      for (int i = 0; i < 4; i++) {
        fa[i] = *(const bf16x8*)(&lAh[kk * 4 + quad][wm * 64 + i * 16 + m16][0]);
        fb[i] = *(const bf16x8*)(&lBh[kk * 4 + quad][wn * 64 + i * 16 + m16][0]);
      }
      #pragma unroll
      for (int i = 0; i < 4; i++)
        #pragma unroll
        for (int j = 0; j < 4; j++)
          acc[i][j] = __builtin_amdgcn_mfma_f32_16x16x32_bf16(fa[i], fb[j], acc[i][j], 0, 0, 0);
      // pass 2: Ahi x Blo (fa reused)
      #pragma unroll
      for (int i = 0; i < 4; i++)
        fb[i] = *(const bf16x8*)(&lBl[kk * 4 + quad][wn * 64 + i * 16 + m16][0]);
      #pragma unroll
      for (int i = 0; i < 4; i++)
        #pragma unroll
        for (int j = 0; j < 4; j++)
          acc[i][j] = __builtin_amdgcn_mfma_f32_16x16x32_bf16(fa[i], fb[j], acc[i][j], 0, 0, 0);
      // pass 3: Alo x Bhi
      #pragma unroll
      for (int i = 0; i < 4; i++) {
        fa[i] = *(const bf16x8*)(&lAl[kk * 4 + quad][wm * 64 + i * 16 + m16][0]);
        fb[i] = *(const bf16x8*)(&lBh[kk * 4 + quad][wn * 64 + i * 16 + m16][0]);
      }
      #pragma unroll
      for (int i = 0; i < 4; i++)
        #pragma unroll
        for (int j = 0; j < 4; j++)
          acc[i][j] = __builtin_amdgcn_mfma_f32_16x16x32_bf16(fa[i], fb[j], acc[i][j], 0, 0, 0);
    }
  }
  // epilogue: D row=(lane>>4)*4+reg, col=lane&15  [m89-verified layout]
  #pragma unroll
  for (int j = 0; j < 4; j++) {
    const int col = n0 + wn * 64 + j * 16 + m16;
    const float bv = bias[col];
    #pragma unroll
    for (int i = 0; i < 4; i++) {
      const int rbase = m0 + wm * 64 + i * 16 + quad * 4;
      #pragma unroll
      for (int r = 0; r < 4; r++) {
        const int row = rbase + r;
        if (row < M) C[(size_t)row * N + col] = acc[i][j][r] + bv;
      }
    }
  }
}

// ---------------------------------------------------------------------------
// 4) Fused attention: one wave per (t, head, 30-row chunk).
//    - k cached in 64 VGPRs with bucket-centre RoPE applied at load
//    - v cached in 64 VGPRs
//    - q RoPE applied at load (pos[n]); softmax over 32 via shuffles
//    - epilogue writes (hi|lo) bf16 split directly in proj-GEMM A layout
// ---------------------------------------------------------------------------
__global__ __launch_bounds__(64) void attn_kernel(
    const float* __restrict__ q, const float* __restrict__ kv,
    const float* __restrict__ pos, ushort* __restrict__ attA) {
  const int chunk = blockIdx.x;   // 0..51
  const int head  = blockIdx.y;   // 0..11
  const int t     = blockIdx.z;   // 0..20
  const int lane  = threadIdx.x;  // 0..63
  const int a = lane & 31, h = lane >> 5;
  const float L2_10000_64 = 13.287712379549449f / 64.0f;  // log2(10000)/64

  // ---- preload k (roped) : lane holds k[a][h*64 .. h*64+63]
  float kreg[64];
  const float* krow = kv + (size_t)(t * NA + a) * (2 * DIM) + head * HD + h * 64;
  #pragma unroll
  for (int j = 0; j < 16; j++) ((float4*)kreg)[j] = ((const float4*)krow)[j];
  const float pk = (a < 16) ? 2.0f : 22.0f;
  #pragma unroll
  for (int j = 0; j < 32; j++) {
    int ip = h * 32 + j;                        // pair index within head_dim
    float fr = exp2f(-(float)ip * L2_10000_64); // 10000^(-ip/64)
    float sn, cs; sincosf(pk * fr, &sn, &cs);
    float x0 = kreg[2 * j], x1 = kreg[2 * j + 1];
    kreg[2 * j]     = x0 * cs - x1 * sn;
    kreg[2 * j + 1] = x1 * cs + x0 * sn;
  }
  // ---- preload v : lane holds v[a][lane], v[a][lane+64]
  float vr0[32], vr1[32];
  const float* vbase = kv + (size_t)(t * NA) * (2 * DIM) + DIM + head * HD;
  #pragma unroll
  for (int aa = 0; aa < 32; aa++) {
    vr0[aa] = vbase[(size_t)aa * (2 * DIM) + lane];
    vr1[aa] = vbase[(size_t)aa * (2 * DIM) + 64 + lane];
  }

  __shared__ float qs[128];
  __shared__ float Ps[32];
  const float myfreq = exp2f(-(float)lane * L2_10000_64);

  for (int r = 0; r < 30; r++) {
    const int n = t * SS + chunk * 30 + r;
    // q load + rope (lane owns pair `lane`: dims 2*lane, 2*lane+1)
    float2 qp = ((const float2*)(q + (size_t)n * DIM + head * HD))[lane];
    float p = pos[n];
    float sn, cs; sincosf(p * myfreq, &sn, &cs);
    qs[2 * lane]     = qp.x * cs - qp.y * sn;
    qs[2 * lane + 1] = qp.y * cs + qp.x * sn;
    __syncthreads();
    // scores: lane (a,h) partial over d in [h*64, h*64+64)
    float accd = 0.f;
    #pragma unroll
    for (int j4 = 0; j4 < 16; j4++) {
      float4 qq = ((const float4*)(qs + h * 64))[j4];   // 2-address broadcast
      accd += qq.x * kreg[j4 * 4] + qq.y * kreg[j4 * 4 + 1] +
              qq.z * kreg[j4 * 4 + 2] + qq.w * kreg[j4 * 4 + 3];
    }
    accd += __shfl_xor(accd, 32);
    accd *= 0.08838834764831845f;    // 1/sqrt(128)
    // softmax over the 32 a-lanes (both halves mirror)
    float mx = accd;
    #pragma unroll
    for (int o = 16; o >= 1; o >>= 1) mx = fmaxf(mx, __shfl_xor(mx, o));
    float e = __expf(accd - mx);
    float sum = e;
    #pragma unroll
    for (int o = 16; o >= 1; o >>= 1) sum += __shfl_xor(sum, o);
    float P = e / sum;
    if (lane < 32) Ps[lane] = P;
    __syncthreads();
    // PV: lane accumulates out[lane], out[lane+64]
    float o0 = 0.f, o1 = 0.f;
    #pragma unroll
    for (int aa = 0; aa < 32; aa++) {
      float pa = Ps[aa];               // broadcast read
      o0 += pa * vr0[aa];
      o1 += pa * vr1[aa];
    }
    // write hi|lo split in proj-GEMM A layout (row length 2*DIM)
    size_t base = (size_t)n * (2 * DIM);
    int c0 = head * HD + lane;
    ushort h0 = bf16hi(o0); ushort l0 = bf16hi(o0 - bf16tof(h0));
    ushort h1 = bf16hi(o1); ushort l1 = bf16hi(o1 - bf16tof(h1));
    attA[base + c0]            = h0;
    attA[base + DIM + c0]      = l0;
    attA[base + c0 + 64]       = h1;
    attA[base + DIM + c0 + 64] = l1;
    __syncthreads();   // protect qs/Ps before next row overwrites
  }
}

// ---------------------------------------------------------------------------
extern "C" void kernel_launch(void* const* d_in, const int* in_sizes, int n_in,
                              void* d_out, int out_size, void* d_ws, size_t ws_size,
                              hipStream_t stream) {
  const float* x      = (const float*)d_in[0];
  const float* enc    = (const float*)d_in[1];
  const float* xmap   = (const float*)d_in[2];
  const float* q_w    = (const float*)d_in[3];
  const float* q_b    = (const float*)d_in[4];
  const float* kv_w   = (const float*)d_in[5];
  const float* kv_b   = (const float*)d_in[6];
  const float* proj_w = (const float*)d_in[7];
  const float* proj_b = (const float*)d_in[8];
  float* out = (float*)d_out;
  char* ws = (char*)d_ws;

  // workspace layout (bytes)
  const size_t OFF_POS  = 0;                           // 32760 f32
  const size_t OFF_APR  = 131072;                      // 32760 x 3072 bf16 (hi|lo)
  const size_t OFF_Q    = OFF_APR + 201277440;         // 32760 x 1536 f32
  const size_t OFF_KV   = OFF_Q   + 201277440;         // 672 x 3072 f32
  const size_t OFF_BQ   = OFF_KV  + 8257536;           // 1536 x 3072 bf16
  const size_t OFF_BKV  = OFF_BQ  + 9437184;           // 3072 x 1536 bf16
  const size_t OFF_BP   = OFF_BKV + 9437184;           // 1536 x 3072 bf16
  const size_t OFF_AKV  = OFF_BP  + 9437184;           // 672 x 1536 bf16
  const size_t TOTAL    = OFF_AKV + 2064384;           // ~421 MB
  if (ws_size < TOTAL) {
    fprintf(stderr, "kernel_launch: ws_size %zu < needed %zu\n", ws_size, TOTAL);
    return;
  }
  float*  pos   = (float*)(ws + OFF_POS);
  ushort* Apr   = (ushort*)(ws + OFF_APR);
  float*  qbuf  = (float*)(ws + OFF_Q);
  float*  kvbuf = (float*)(ws + OFF_KV);
  ushort* Bq    = (ushort*)(ws + OFF_BQ);
  ushort* Bkv   = (ushort*)(ws + OFF_BKV);
  ushort* Bp    = (ushort*)(ws + OFF_BP);
  ushort* Akv   = (ushort*)(ws + OFF_AKV);

  // 1) routing positions
  minmax_pos_kernel<<<1, 1024, 0, stream>>>(xmap, pos, TOK);
  // 2) hi/lo conversions
  conv_hilo_kernel<<<2048, 256, 0, stream>>>(x,      Apr, TOK,    DIM);
  conv_hilo_kernel<<<256,  256, 0, stream>>>(q_w,    Bq,  DIM,    DIM);
  conv_hilo_kernel<<<256,  256, 0, stream>>>(kv_w,   Bkv, 2*DIM,  ENCD);
  conv_hilo_kernel<<<64,   256, 0, stream>>>(enc,    Akv, KVROWS, ENCD);
  conv_hilo_kernel<<<256,  256, 0, stream>>>(proj_w, Bp,  DIM,    DIM);
  // 3) Q = x @ q_w^T + q_b
  gemm_bf16s_kernel<<<dim3(DIM/128, (TOK+127)/128), 256, 0, stream>>>(
      Apr, Bq, q_b, qbuf, TOK, DIM, DIM);
  // 4) KV = enc @ kv_w^T + kv_b
  gemm_bf16s_kernel<<<dim3(2*DIM/128, (KVROWS+127)/128), 256, 0, stream>>>(
      Akv, Bkv, kv_b, kvbuf, KVROWS, 2*DIM, ENCD);
  // 5) fused rope+attention, writes hi|lo att into Apr (x-conv dead by now)
  attn_kernel<<<dim3(52, HEADS, NT), 64, 0, stream>>>(qbuf, kvbuf, pos, Apr);
  // 6) out = att @ proj_w^T + proj_b
  gemm_bf16s_kernel<<<dim3(DIM/128, (TOK+127)/128), 256, 0, stream>>>(
      Apr, Bp, proj_b, out, TOK, DIM, DIM);
}

// Round 3
// 1701.884 us; speedup vs baseline: 1.7224x; 1.4298x over previous
//
#include <hip/hip_runtime.h>
#include <cstdio>
#include <cstdint>

// Problem constants (from setup_inputs; fixed for this problem)
#define TOK   32760      // N_t * S
#define DIM   1536
#define ENCD  768
#define NA    32
#define NT    21
#define SS    1560
#define HEADS 12
#define HD    128
#define KVROWS (NT * NA)   // 672

using f32x4  = __attribute__((ext_vector_type(4))) float;
using bf16x8 = __attribute__((ext_vector_type(8))) short;

__device__ __forceinline__ ushort bf16hi(float f) {
  unsigned u = __float_as_uint(f);
  return (ushort)((u + 0x7FFFu + ((u >> 16) & 1u)) >> 16);   // RNE
}
__device__ __forceinline__ float bf16tof(ushort h) {
  return __uint_as_float(((unsigned)h) << 16);
}

__device__ __forceinline__ void gload16(const void* g, void* l) {
  __builtin_amdgcn_global_load_lds((const __attribute__((address_space(1))) void*)g,
                                   (__attribute__((address_space(3))) void*)l,
                                   16, 0, 0);
}

// ---------------------------------------------------------------------------
// 1) min/max of the two attn-map rows + per-token rotary position
// ---------------------------------------------------------------------------
__global__ __launch_bounds__(1024) void minmax_pos_kernel(
    const float* __restrict__ m, float* __restrict__ pos, int N) {
  __shared__ float red[4][16];
  __shared__ float fin[4];
  int tid = threadIdx.x;
  float mn0 = 3.4e38f, mx0 = -3.4e38f, mn1 = 3.4e38f, mx1 = -3.4e38f;
  for (int i = tid; i < N; i += 1024) {
    float a = m[i], b = m[N + i];
    mn0 = fminf(mn0, a); mx0 = fmaxf(mx0, a);
    mn1 = fminf(mn1, b); mx1 = fmaxf(mx1, b);
  }
  #pragma unroll
  for (int o = 32; o >= 1; o >>= 1) {
    mn0 = fminf(mn0, __shfl_xor(mn0, o)); mx0 = fmaxf(mx0, __shfl_xor(mx0, o));
    mn1 = fminf(mn1, __shfl_xor(mn1, o)); mx1 = fmaxf(mx1, __shfl_xor(mx1, o));
  }
  int wid = tid >> 6, ln = tid & 63;
  if (ln == 0) { red[0][wid] = mn0; red[1][wid] = mx0; red[2][wid] = mn1; red[3][wid] = mx1; }
  __syncthreads();
  if (tid == 0) {
    float a = red[0][0], b = red[1][0], c = red[2][0], d = red[3][0];
    for (int i = 1; i < 16; i++) {
      a = fminf(a, red[0][i]); b = fmaxf(b, red[1][i]);
      c = fminf(c, red[2][i]); d = fmaxf(d, red[3][i]);
    }
    fin[0] = a; fin[1] = b; fin[2] = c; fin[3] = d;
  }
  __syncthreads();
  float mn0f = fin[0], sc0 = 4.0f / (fin[1] - fin[0] + 1e-8f);
  float mn1f = fin[2], sc1 = 4.0f / (fin[3] - fin[2] + 1e-8f);
  for (int i = tid; i < N; i += 1024) {
    float a = m[i], b = m[N + i];
    float h1 = (a - mn0f) * sc0;            // [0,4]
    float h2 = (b - mn1f) * sc1 + 20.0f;    // [20,24]
    pos[i] = (a >= b) ? h1 : h2;
  }
}

// ---------------------------------------------------------------------------
// 2) fp32 -> (bf16 hi | bf16 lo) split, rows of length K -> rows of length 2K
// ---------------------------------------------------------------------------
__global__ void conv_hilo_kernel(const float* __restrict__ in, ushort* __restrict__ out,
                                 int M, int K) {
  int total4 = M * (K / 4);
  for (int idx = blockIdx.x * blockDim.x + threadIdx.x; idx < total4;
       idx += gridDim.x * blockDim.x) {
    int e = idx * 4;
    int row = e / K;
    int k = e - row * K;
    float4 v = *(const float4*)(in + e);
    float fs[4] = {v.x, v.y, v.z, v.w};
    ushort hs[4], ls[4];
    #pragma unroll
    for (int t = 0; t < 4; t++) {
      hs[t] = bf16hi(fs[t]);
      float hf = bf16tof(hs[t]);
      ls[t] = bf16hi(fs[t] - hf);
    }
    ushort* po = out + (size_t)row * (2 * K) + k;
    *(ushort4*)(po)     = make_ushort4(hs[0], hs[1], hs[2], hs[3]);
    *(ushort4*)(po + K) = make_ushort4(ls[0], ls[1], ls[2], ls[3]);
  }
}

// ---------------------------------------------------------------------------
// 3) Split-bf16 NT GEMM:  C[M,N] = A[M,K] * B[N,K]^T + bias,  fp32-accurate via
//    3 terms: Ahi*Bhi + Ahi*Blo + Alo*Bhi.  A,B stored as (hi|lo) rows of 2K.
//    R2->R3: coalesced staging. Each global_load_lds instruction now covers
//    8 rows x 128 B contiguous (8 cachelines) instead of 64 rows x 16 B
//    (64 transactions). LDS tile layout is row-major [row][64 ushort] with the
//    16 B granule slot XOR-swizzled by (row&7); fragment reads un-swizzle with
//    slot = (kk*4+quad) ^ (m16&7).
// ---------------------------------------------------------------------------
__global__ __launch_bounds__(256, 2) void gemm_bf16s_kernel(
    const ushort* __restrict__ A, const ushort* __restrict__ B,
    const float* __restrict__ bias, float* __restrict__ C,
    int M, int N, int K) {
  __shared__ __align__(16) ushort lAh[128][64];   // 16 KB, row = 128 B
  __shared__ __align__(16) ushort lAl[128][64];   // 16 KB
  __shared__ __align__(16) ushort lBh[128][64];   // 16 KB
  __shared__ __align__(16) ushort lBl[128][64];   // 16 KB
  const int tid = threadIdx.x;
  const int lane = tid & 63;
  const int w = tid >> 6;          // wave 0..3
  const int wm = w >> 1, wn = w & 1;
  const int quad = lane >> 4, m16 = lane & 15;
  // staging lane decomposition: 8 rows x 8 granules per instruction
  const int r_off = lane >> 3;          // row within 8-row group
  const int g     = lane & 7;           // LDS granule slot
  const int gg8   = (g ^ r_off) * 8;    // swizzled global granule (ushort offset)

  // XCD-aware swizzle: keep a full row panel (all nx column tiles) on one XCD
  int bx = blockIdx.x, by = blockIdx.y;
  {
    const int nx = gridDim.x, ny = gridDim.y;
    if ((ny & 7) == 0) {
      int flat = by * nx + bx;
      int xcd = flat & 7, s = flat >> 3;
      int panel = s / nx;
      bx = s - panel * nx;
      by = panel * 8 + xcd;
    }
  }
  const int m0 = by * 128, n0 = bx * 128;
  const int lda = 2 * K;

  f32x4 acc[4][4];
  #pragma unroll
  for (int i = 0; i < 4; i++)
    #pragma unroll
    for (int j = 0; j < 4; j++) acc[i][j] = (f32x4){0.f, 0.f, 0.f, 0.f};

  const int nIter = K / 64;
  for (int kt = 0; kt < nIter; kt++) {
    const int kH = kt * 64;        // hi half
    const int kL = K + kt * 64;    // lo half
    __syncthreads();               // prior compute done before overwrite
    #pragma unroll
    for (int i = 0; i < 4; i++) {
      const int ss = w * 4 + i;    // staging instr 0..15 per tile
      int rowA = m0 + ss * 8 + r_off; if (rowA >= M) rowA = M - 1;
      const ushort* ar = A + (size_t)rowA * lda;
      gload16(ar + kH + gg8, (char*)&lAh[0][0] + ss * 1024);
      gload16(ar + kL + gg8, (char*)&lAl[0][0] + ss * 1024);
      int rowB = n0 + ss * 8 + r_off; if (rowB >= N) rowB = N - 1;
      const ushort* br = B + (size_t)rowB * lda;
      gload16(br + kH + gg8, (char*)&lBh[0][0] + ss * 1024);
      gload16(br + kL + gg8, (char*)&lBl[0][0] + ss * 1024);
    }
    __syncthreads();               // vmcnt(0) drain -> all 4 tiles ready
    #pragma unroll
    for (int kk = 0; kk < 2; kk++) {
      const int slot8 = (((kk * 4 + quad) ^ (m16 & 7)) * 8);
      bf16x8 fah[4], fbh[4], ft[4];
      // pass 1: Ahi x Bhi
      #pragma unroll
      for (int i = 0; i < 4; i++) {
        fah[i] = *(const bf16x8*)(&lAh[wm * 64 + i * 16 + m16][slot8]);
        fbh[i] = *(const bf16x8*)(&lBh[wn * 64 + i * 16 + m16][slot8]);
      }
      #pragma unroll
      for (int i = 0; i < 4; i++)
        #pragma unroll
        for (int j = 0; j < 4; j++)
          acc[i][j] = __builtin_amdgcn_mfma_f32_16x16x32_bf16(fah[i], fbh[j], acc[i][j], 0, 0, 0);
      // pass 2: Ahi x Blo (fah reused)
      #pragma unroll
      for (int i = 0; i < 4; i++)
        ft[i] = *(const bf16x8*)(&lBl[wn * 64 + i * 16 + m16][slot8]);
      #pragma unroll
      for (int i = 0; i < 4; i++)
        #pragma unroll
        for (int j = 0; j < 4; j++)
          acc[i][j] = __builtin_amdgcn_mfma_f32_16x16x32_bf16(fah[i], ft[j], acc[i][j], 0, 0, 0);
      // pass 3: Alo x Bhi (fbh reused)
      #pragma unroll
      for (int i = 0; i < 4; i++)
        ft[i] = *(const bf16x8*)(&lAl[wm * 64 + i * 16 + m16][slot8]);
      #pragma unroll
      for (int i = 0; i < 4; i++)
        #pragma unroll
        for (int j = 0; j < 4; j++)
          acc[i][j] = __builtin_amdgcn_mfma_f32_16x16x32_bf16(ft[i], fbh[j], acc[i][j], 0, 0, 0);
    }
  }
  // epilogue: D row=(lane>>4)*4+reg, col=lane&15  [m89-verified layout]
  #pragma unroll
  for (int j = 0; j < 4; j++) {
    const int col = n0 + wn * 64 + j * 16 + m16;
    const float bv = bias[col];
    #pragma unroll
    for (int i = 0; i < 4; i++) {
      const int rbase = m0 + wm * 64 + i * 16 + quad * 4;
      #pragma unroll
      for (int r = 0; r < 4; r++) {
        const int row = rbase + r;
        if (row < M) C[(size_t)row * N + col] = acc[i][j][r] + bv;
      }
    }
  }
}

// ---------------------------------------------------------------------------
// 4) Fused attention: one wave per (t, head, 30-row chunk).
// ---------------------------------------------------------------------------
__global__ __launch_bounds__(64) void attn_kernel(
    const float* __restrict__ q, const float* __restrict__ kv,
    const float* __restrict__ pos, ushort* __restrict__ attA) {
  const int chunk = blockIdx.x;   // 0..51
  const int head  = blockIdx.y;   // 0..11
  const int t     = blockIdx.z;   // 0..20
  const int lane  = threadIdx.x;  // 0..63
  const int a = lane & 31, h = lane >> 5;
  const float L2_10000_64 = 13.287712379549449f / 64.0f;  // log2(10000)/64

  // ---- preload k (roped) : lane holds k[a][h*64 .. h*64+63]
  float kreg[64];
  const float* krow = kv + (size_t)(t * NA + a) * (2 * DIM) + head * HD + h * 64;
  #pragma unroll
  for (int j = 0; j < 16; j++) ((float4*)kreg)[j] = ((const float4*)krow)[j];
  const float pk = (a < 16) ? 2.0f : 22.0f;
  #pragma unroll
  for (int j = 0; j < 32; j++) {
    int ip = h * 32 + j;                        // pair index within head_dim
    float fr = exp2f(-(float)ip * L2_10000_64); // 10000^(-ip/64)
    float sn, cs; sincosf(pk * fr, &sn, &cs);
    float x0 = kreg[2 * j], x1 = kreg[2 * j + 1];
    kreg[2 * j]     = x0 * cs - x1 * sn;
    kreg[2 * j + 1] = x1 * cs + x0 * sn;
  }
  // ---- preload v : lane holds v[a][lane], v[a][lane+64]
  float vr0[32], vr1[32];
  const float* vbase = kv + (size_t)(t * NA) * (2 * DIM) + DIM + head * HD;
  #pragma unroll
  for (int aa = 0; aa < 32; aa++) {
    vr0[aa] = vbase[(size_t)aa * (2 * DIM) + lane];
    vr1[aa] = vbase[(size_t)aa * (2 * DIM) + 64 + lane];
  }

  __shared__ float qs[128];
  __shared__ float Ps[32];
  const float myfreq = exp2f(-(float)lane * L2_10000_64);

  for (int r = 0; r < 30; r++) {
    const int n = t * SS + chunk * 30 + r;
    // q load + rope (lane owns pair `lane`: dims 2*lane, 2*lane+1)
    float2 qp = ((const float2*)(q + (size_t)n * DIM + head * HD))[lane];
    float p = pos[n];
    float sn, cs; sincosf(p * myfreq, &sn, &cs);
    qs[2 * lane]     = qp.x * cs - qp.y * sn;
    qs[2 * lane + 1] = qp.y * cs + qp.x * sn;
    __syncthreads();
    // scores: lane (a,h) partial over d in [h*64, h*64+64)
    float accd = 0.f;
    #pragma unroll
    for (int j4 = 0; j4 < 16; j4++) {
      float4 qq = ((const float4*)(qs + h * 64))[j4];   // 2-address broadcast
      accd += qq.x * kreg[j4 * 4] + qq.y * kreg[j4 * 4 + 1] +
              qq.z * kreg[j4 * 4 + 2] + qq.w * kreg[j4 * 4 + 3];
    }
    accd += __shfl_xor(accd, 32);
    accd *= 0.08838834764831845f;    // 1/sqrt(128)
    // softmax over the 32 a-lanes (both halves mirror)
    float mx = accd;
    #pragma unroll
    for (int o = 16; o >= 1; o >>= 1) mx = fmaxf(mx, __shfl_xor(mx, o));
    float e = __expf(accd - mx);
    float sum = e;
    #pragma unroll
    for (int o = 16; o >= 1; o >>= 1) sum += __shfl_xor(sum, o);
    float P = e / sum;
    if (lane < 32) Ps[lane] = P;
    __syncthreads();
    // PV: lane accumulates out[lane], out[lane+64]
    float o0 = 0.f, o1 = 0.f;
    #pragma unroll
    for (int aa = 0; aa < 32; aa++) {
      float pa = Ps[aa];               // broadcast read
      o0 += pa * vr0[aa];
      o1 += pa * vr1[aa];
    }
    // write hi|lo split in proj-GEMM A layout (row length 2*DIM)
    size_t base = (size_t)n * (2 * DIM);
    int c0 = head * HD + lane;
    ushort h0 = bf16hi(o0); ushort l0 = bf16hi(o0 - bf16tof(h0));
    ushort h1 = bf16hi(o1); ushort l1 = bf16hi(o1 - bf16tof(h1));
    attA[base + c0]            = h0;
    attA[base + DIM + c0]      = l0;
    attA[base + c0 + 64]       = h1;
    attA[base + DIM + c0 + 64] = l1;
    __syncthreads();   // protect qs/Ps before next row overwrites
  }
}

// ---------------------------------------------------------------------------
extern "C" void kernel_launch(void* const* d_in, const int* in_sizes, int n_in,
                              void* d_out, int out_size, void* d_ws, size_t ws_size,
                              hipStream_t stream) {
  const float* x      = (const float*)d_in[0];
  const float* enc    = (const float*)d_in[1];
  const float* xmap   = (const float*)d_in[2];
  const float* q_w    = (const float*)d_in[3];
  const float* q_b    = (const float*)d_in[4];
  const float* kv_w   = (const float*)d_in[5];
  const float* kv_b   = (const float*)d_in[6];
  const float* proj_w = (const float*)d_in[7];
  const float* proj_b = (const float*)d_in[8];
  float* out = (float*)d_out;
  char* ws = (char*)d_ws;

  // workspace layout (bytes)
  const size_t OFF_POS  = 0;                           // 32760 f32
  const size_t OFF_APR  = 131072;                      // 32760 x 3072 bf16 (hi|lo)
  const size_t OFF_Q    = OFF_APR + 201277440;         // 32760 x 1536 f32
  const size_t OFF_KV   = OFF_Q   + 201277440;         // 672 x 3072 f32
  const size_t OFF_BQ   = OFF_KV  + 8257536;           // 1536 x 3072 bf16
  const size_t OFF_BKV  = OFF_BQ  + 9437184;           // 3072 x 1536 bf16
  const size_t OFF_BP   = OFF_BKV + 9437184;           // 1536 x 3072 bf16
  const size_t OFF_AKV  = OFF_BP  + 9437184;           // 672 x 1536 bf16
  const size_t TOTAL    = OFF_AKV + 2064384;           // ~421 MB
  if (ws_size < TOTAL) {
    fprintf(stderr, "kernel_launch: ws_size %zu < needed %zu\n", ws_size, TOTAL);
    return;
  }
  float*  pos   = (float*)(ws + OFF_POS);
  ushort* Apr   = (ushort*)(ws + OFF_APR);
  float*  qbuf  = (float*)(ws + OFF_Q);
  float*  kvbuf = (float*)(ws + OFF_KV);
  ushort* Bq    = (ushort*)(ws + OFF_BQ);
  ushort* Bkv   = (ushort*)(ws + OFF_BKV);
  ushort* Bp    = (ushort*)(ws + OFF_BP);
  ushort* Akv   = (ushort*)(ws + OFF_AKV);

  // 1) routing positions
  minmax_pos_kernel<<<1, 1024, 0, stream>>>(xmap, pos, TOK);
  // 2) hi/lo conversions
  conv_hilo_kernel<<<2048, 256, 0, stream>>>(x,      Apr, TOK,    DIM);
  conv_hilo_kernel<<<256,  256, 0, stream>>>(q_w,    Bq,  DIM,    DIM);
  conv_hilo_kernel<<<256,  256, 0, stream>>>(kv_w,   Bkv, 2*DIM,  ENCD);
  conv_hilo_kernel<<<64,   256, 0, stream>>>(enc,    Akv, KVROWS, ENCD);
  conv_hilo_kernel<<<256,  256, 0, stream>>>(proj_w, Bp,  DIM,    DIM);
  // 3) Q = x @ q_w^T + q_b
  gemm_bf16s_kernel<<<dim3(DIM/128, (TOK+127)/128), 256, 0, stream>>>(
      Apr, Bq, q_b, qbuf, TOK, DIM, DIM);
  // 4) KV = enc @ kv_w^T + kv_b
  gemm_bf16s_kernel<<<dim3(2*DIM/128, (KVROWS+127)/128), 256, 0, stream>>>(
      Akv, Bkv, kv_b, kvbuf, KVROWS, 2*DIM, ENCD);
  // 5) fused rope+attention, writes hi|lo att into Apr (x-conv dead by now)
  attn_kernel<<<dim3(52, HEADS, NT), 64, 0, stream>>>(qbuf, kvbuf, pos, Apr);
  // 6) out = att @ proj_w^T + proj_b
  gemm_bf16s_kernel<<<dim3(DIM/128, (TOK+127)/128), 256, 0, stream>>>(
      Apr, Bp, proj_b, out, TOK, DIM, DIM);
}